// Round 7
// baseline (61.917 us; speedup 1.0000x reference)
//
#include <hip/hip_runtime.h>
#include <math.h>

#define NN 147456   // 384*384
#define Nn 384
#define Dd 256
#define Cc 12
#define NTILE 144   // 12x12 tiles per matrix

__device__ __forceinline__ float kern5(float d, const float* __restrict__ ibw) {
    float acc = 0.f;
#pragma unroll
    for (int k = 0; k < 5; k++) {
        float r = fminf(fmaxf(d * ibw[k], 1e-5f), 1e5f);
        acc += __expf(-r);
    }
    return acc;
}

__device__ __forceinline__ float blockReduceSum(float v, float* sh) {
#pragma unroll
    for (int o = 32; o; o >>= 1) v += __shfl_xor(v, o, 64);
    __syncthreads();                       // protect sh reuse across calls
    if ((threadIdx.x & 63) == 0) sh[threadIdx.x >> 6] = v;
    __syncthreads();
    float r = 0.f;
    if (threadIdx.x == 0) {
        int nw = (int)(blockDim.x >> 6);
        for (int w = 0; w < nw; w++) r += sh[w];
    }
    return r;
}

// ---------- kernel 1: cdist + per-tile stats partials (fused) ----------
// z=0: E_ss (src,src) -> P0[tile][144] = per-(s,t) sums
// z=1: E_tt (tgt,tgt) -> P1[tile][12]  = per-c  pt_i E pt_j sums
// z=2: E_st (src,tgt) -> P2[tile][12]  = per-c  (i in c) E pt_j sums
// Partials are written UNCONDITIONALLY per tile -> no global zeroing needed.
__global__ __launch_bounds__(256) void cdist_stats_kernel(
        const float* __restrict__ sx, const float* __restrict__ tx,
        const int* __restrict__ ys, const float* __restrict__ pt,
        float* __restrict__ Ebase, float* __restrict__ P0,
        float* __restrict__ P1, float* __restrict__ P2,
        float* __restrict__ out) {
    int z = blockIdx.z;
    int tid = threadIdx.x;
    int i0 = blockIdx.y * 32, j0 = blockIdx.x * 32;
    int tileIdx = blockIdx.y * 12 + blockIdx.x;
    // zero the output accumulators (eval runs strictly after this kernel)
    if (z == 0 && tileIdx == 0 && tid < 2) out[tid] = 0.f;

    const float* X = (z == 1) ? tx : sx;
    const float* Y = (z == 0) ? sx : tx;
    float* Eo = Ebase + z * NN;

    __shared__ float As[32][33];
    __shared__ float Bs[32][33];
    __shared__ float red[144];
    __shared__ int   ysh[32];
    __shared__ float ptish[384];
    if (tid < 32) ysh[tid] = ys[i0 + tid];       // row classes (z==0, z==2)
    if (tid < 144) red[tid] = 0.f;
    if (z == 1)
        for (int q = tid; q < 384; q += 256) ptish[q] = pt[i0 * 12 + q];

    int tj = tid & 31, ti = tid >> 5;  // 32 cols x 8 rows
    float acc[4] = {0.f, 0.f, 0.f, 0.f};
    for (int kk = 0; kk < Dd; kk += 32) {
#pragma unroll
        for (int p = 0; p < 4; p++) {
            int idx = tid + p * 256;
            int r = idx >> 5, k = idx & 31;
            As[r][k] = X[(i0 + r) * Dd + kk + k];
            Bs[r][k] = Y[(j0 + r) * Dd + kk + k];
        }
        __syncthreads();
#pragma unroll
        for (int m = 0; m < 4; m++) {
            int r = ti + m * 8;
            float a = 0.f;
#pragma unroll
            for (int k = 0; k < 32; k++) {
                float d = As[r][k] - Bs[tj][k];
                a = fmaf(d, d, a);
            }
            acc[m] += a;
        }
        __syncthreads();
    }
    float e[4];
#pragma unroll
    for (int m = 0; m < 4; m++) {
        e[m] = sqrtf(acc[m]);
        Eo[(i0 + ti + m * 8) * Nn + j0 + tj] = e[m];
    }

    // ---- per-tile stats (red[] zero-writes are visible via the loop barriers) ----
    if (z == 0) {
        int t = ys[j0 + tj];                       // column class
#pragma unroll
        for (int m = 0; m < 4; m++)
            atomicAdd(&red[ysh[ti + m * 8] * 12 + t], e[m]);
        __syncthreads();
        if (tid < 144) P0[tileIdx * 144 + tid] = red[tid];
    } else {
        // pt row (j0+tj): 48B -> 3x float4
        const float4* p4 = (const float4*)(pt + (j0 + tj) * 12);
        float4 pa = p4[0], pb = p4[1], pc = p4[2];
        float pv[12] = {pa.x, pa.y, pa.z, pa.w, pb.x, pb.y, pb.z, pb.w,
                        pc.x, pc.y, pc.z, pc.w};
#pragma unroll
        for (int c = 0; c < 12; c++) {
            float a = 0.f;
            if (z == 1) {
#pragma unroll
                for (int m = 0; m < 4; m++)
                    a = fmaf(e[m], ptish[(ti + m * 8) * 12 + c], a);
            } else {
#pragma unroll
                for (int m = 0; m < 4; m++)
                    a += (ysh[ti + m * 8] == c) ? e[m] : 0.f;
            }
            float v = a * pv[c];
#pragma unroll
            for (int o = 32; o; o >>= 1) v += __shfl_xor(v, o, 64);
            if ((tid & 63) == 0) atomicAdd(&red[c], v);
        }
        __syncthreads();
        if (tid < 12) {
            if (z == 1) P1[tileIdx * 12 + tid] = red[tid];
            else        P2[tileIdx * 12 + tid] = red[tid];
        }
    }
}

// ---------- kernel 2: eval with inline prep (k1+k2+k3+inter) ----------
// One block per row i (384 blocks x 384 threads). Prologue reduces the
// per-tile partials into the class stats this block needs (s = ys[i] is
// block-uniform), derives bandwidth tables in LDS, then evaluates all
// RBF terms for pairs (i, j).
__global__ __launch_bounds__(384) void eval_kernel(
        const float* __restrict__ E, const int* __restrict__ ys,
        const float* __restrict__ pt, const float* __restrict__ P0,
        const float* __restrict__ P1, const float* __restrict__ P2,
        float* __restrict__ out) {
    int i = blockIdx.x;
    int j = threadIdx.x;
    int s = ys[i];                          // uniform broadcast load
    __shared__ float st48[48];              // 0:sss(diag) 12:rowS 24:stt 36:sstd
    __shared__ float s_cs[12], s_ct[12];
    __shared__ float sh_ibwin[60];          // 1/bw(g_in), all classes
    __shared__ float sh_ibw2s[60];          // 1/bw(g2), row s
    __shared__ float sh_invptt[12];
    __shared__ float sh_invccs[12];         // 1/(cs[s]*cs[t'])
    __shared__ float sh_pti[12];            // pt[i][*]
    __shared__ float red[8];
    if (j < 48) st48[j] = 0.f;
    else if (j >= 64 && j < 76)  s_cs[j - 64] = 0.f;
    else if (j >= 80 && j < 92)  s_ct[j - 80] = 0.f;
    else if (j >= 96 && j < 108) sh_pti[j - 96] = pt[i * 12 + (j - 96)];

    int t = ys[j];
    const float4* p4 = (const float4*)(pt + j * 12);
    float4 pa = p4[0], pb = p4[1], pc = p4[2];
    float ptj[12] = {pa.x, pa.y, pa.z, pa.w, pb.x, pb.y, pb.z, pb.w,
                     pc.x, pc.y, pc.z, pc.w};
    float e_ss = E[i * Nn + j];
    float e_tt = E[NN + i * Nn + j];
    float e_st = E[2 * NN + i * Nn + j];
    __syncthreads();

    // ---- cs / ct ----
    atomicAdd(&s_cs[t], 1.f);
#pragma unroll
    for (int c = 0; c < 12; c++) {
        float v = ptj[c];
#pragma unroll
        for (int o = 32; o; o >>= 1) v += __shfl_xor(v, o, 64);
        if ((j & 63) == 0) atomicAdd(&s_ct[c], v);
    }
    // ---- reduce per-tile partials: 48 targets x 8 threads each ----
    {
        int g = j % 48, k = j / 48;
        float v = 0.f;
        if (g < 12) {
            for (int tl = k; tl < NTILE; tl += 8) v += P0[tl * 144 + g * 13];
        } else if (g < 24) {
            int tp = g - 12;
            for (int tl = k; tl < NTILE; tl += 8) v += P0[tl * 144 + s * 12 + tp];
        } else if (g < 36) {
            int c = g - 24;
            for (int tl = k; tl < NTILE; tl += 8) v += P1[tl * 12 + c];
        } else {
            int c = g - 36;
            for (int tl = k; tl < NTILE; tl += 8) v += P2[tl * 12 + c];
        }
        atomicAdd(&st48[g], v);
    }
    __syncthreads();
    // ---- derive bandwidth tables ----
    const float MUP[5] = {0.25f, 0.5f, 1.f, 2.f, 4.f};
    if (j < 12) {
        int c = j;
        float cs = s_cs[c], ct2 = s_ct[c];
        float g = (st48[c] + st48[24 + c] + 2.f * st48[36 + c])
                  / ((cs + ct2) * (cs + ct2));
#pragma unroll
        for (int k = 0; k < 5; k++)
            sh_ibwin[c * 5 + k] = 1.f / fmaxf(g * MUP[k], 1e-5f);
        sh_invptt[c] = 1.f / (ct2 * ct2);
    } else if (j >= 64 && j < 76) {
        int tp = j - 64;
        float css = s_cs[s], cst = s_cs[tp];
        float g2 = (st48[s] + st48[tp] + 2.f * st48[12 + tp])
                   / ((css + cst) * (css + cst));
#pragma unroll
        for (int k = 0; k < 5; k++)
            sh_ibw2s[tp * 5 + k] = 1.f / fmaxf(g2 * MUP[k], 1e-5f);
        sh_invccs[tp] = 1.f / (css * cst);
    }
    __syncthreads();
    float invpss_s = 1.f / (s_cs[s] * s_cs[s]);
    float invcst_s = 1.f / (s_cs[s] * s_ct[s]);

    float si = 0.f, se = 0.f;
    // ---- k2: target-target, soft probs, all 12 classes ----
#pragma unroll
    for (int c = 0; c < 12; c++) {
        float w = sh_pti[c] * ptj[c];
        si = fmaf(kern5(e_tt * w, &sh_ibwin[c * 5]) * w, sh_invptt[c], si);
    }
    // ---- k3: source-target, diagonal pair (class s) ----
    {
        float w = 0.f;                     // ptj[s] via unrolled select
#pragma unroll
        for (int c = 0; c < 12; c++) w = (c == s) ? ptj[c] : w;
        si = fmaf(-2.f * kern5(e_st * w, &sh_ibwin[s * 5]) * w, invcst_s, si);
    }
    // ---- k1 + inter on E_ss ----
    if (t == s) {
        si = fmaf(kern5(e_ss, &sh_ibwin[s * 5]), invpss_s, si);
        float ts = -kern5(e_ss, &sh_ibw2s[s * 5]);  // subtract tp==s term
#pragma unroll
        for (int tp = 0; tp < 12; tp++)
            ts += kern5(e_ss, &sh_ibw2s[tp * 5]);
        se = fmaf(2.f * ts, invpss_s, se);
    } else {
        se = fmaf(-2.f * kern5(e_ss, &sh_ibw2s[t * 5]), sh_invccs[t], se);
    }
    si = blockReduceSum(si, red);
    se = blockReduceSum(se, red);
    if (j == 0) {
        atomicAdd(&out[0], si * (1.f / 12.f));
        atomicAdd(&out[1], se * (1.f / 132.f));   // C*C - C = 132
    }
}

extern "C" void kernel_launch(void* const* d_in, const int* in_sizes, int n_in,
                              void* d_out, int out_size, void* d_ws, size_t ws_size,
                              hipStream_t stream) {
    (void)in_sizes; (void)n_in; (void)out_size; (void)ws_size;
    const float* sx = (const float*)d_in[0];   // src_x (384,256) f32
    const float* tx = (const float*)d_in[1];   // tgt_x (384,256) f32
    const int*   ys = (const int*)d_in[2];     // src_y (384,) i32
    const float* pt = (const float*)d_in[3];   // tgt_y (384,12) f32
    float* out = (float*)d_out;                // [intra, inter] f32
    float* ws  = (float*)d_ws;
    float* E   = ws;                           // 3 * NN floats
    float* P0  = ws + 3 * NN;                  // 144*144
    float* P1  = P0 + NTILE * 144;             // 144*12
    float* P2  = P1 + NTILE * 12;              // 144*12

    cdist_stats_kernel<<<dim3(12, 12, 3), 256, 0, stream>>>(sx, tx, ys, pt,
                                                            E, P0, P1, P2, out);
    eval_kernel<<<384, 384, 0, stream>>>(E, ys, pt, P0, P1, P2, out);
}

// Round 8
// 48.847 us; speedup vs baseline: 1.2676x; 1.2676x over previous
//
#include <hip/hip_runtime.h>
#include <math.h>

#define NN 147456   // 384*384
#define Nn 384
#define Dd 256
#define Cc 12
#define NTILE 144   // 12x12 tiles per matrix (32x32 each)

__device__ __forceinline__ float kern5(float d, const float* __restrict__ ibw) {
    float acc = 0.f;
#pragma unroll
    for (int k = 0; k < 5; k++) {
        float r = fminf(fmaxf(d * ibw[k], 1e-5f), 1e5f);
        acc += __expf(-r);
    }
    return acc;
}

__device__ __forceinline__ float blockReduceSum(float v, float* sh) {
#pragma unroll
    for (int o = 32; o; o >>= 1) v += __shfl_xor(v, o, 64);
    __syncthreads();                       // protect sh reuse across calls
    if ((threadIdx.x & 63) == 0) sh[threadIdx.x >> 6] = v;
    __syncthreads();
    float r = 0.f;
    if (threadIdx.x == 0) {
        int nw = (int)(blockDim.x >> 6);
        for (int w = 0; w < nw; w++) r += sh[w];
    }
    return r;
}

// ---------- kernel 1: cdist + per-tile stats partials (fused, TRANSPOSED) ----------
// z=0: E_ss (src,src) -> P0T[stat(144)][tile(144)]  per-(s,t) sums
// z=1: E_tt (tgt,tgt) -> P1T[c(12)][tile(144)]      pt_i E pt_j sums
// z=2: E_st (src,tgt) -> P2T[c(12)][tile(144)]      (i in c) E pt_j sums
// Partials are written UNCONDITIONALLY per tile -> no global zeroing needed.
// Transposed layout makes the eval-side reduction fully coalesced.
__global__ __launch_bounds__(256) void cdist_stats_kernel(
        const float* __restrict__ sx, const float* __restrict__ tx,
        const int* __restrict__ ys, const float* __restrict__ pt,
        float* __restrict__ Ebase, float* __restrict__ P0T,
        float* __restrict__ P1T, float* __restrict__ P2T,
        float* __restrict__ out) {
    int z = blockIdx.z;
    int tid = threadIdx.x;
    int i0 = blockIdx.y * 32, j0 = blockIdx.x * 32;
    int tileIdx = blockIdx.y * 12 + blockIdx.x;
    // zero the output accumulators (eval runs strictly after this kernel)
    if (z == 0 && tileIdx == 0 && tid < 2) out[tid] = 0.f;

    const float* X = (z == 1) ? tx : sx;
    const float* Y = (z == 0) ? sx : tx;
    float* Eo = Ebase + z * NN;

    __shared__ float As[32][33];
    __shared__ float Bs[32][33];
    __shared__ float red[144];
    __shared__ int   ysh[32];
    __shared__ float ptish[384];
    if (tid < 32) ysh[tid] = ys[i0 + tid];       // row classes (z==0, z==2)
    if (tid < 144) red[tid] = 0.f;
    if (z == 1)
        for (int q = tid; q < 384; q += 256) ptish[q] = pt[i0 * 12 + q];

    int tj = tid & 31, ti = tid >> 5;  // 32 cols x 8 rows
    float acc[4] = {0.f, 0.f, 0.f, 0.f};
    for (int kk = 0; kk < Dd; kk += 32) {
#pragma unroll
        for (int p = 0; p < 4; p++) {
            int idx = tid + p * 256;
            int r = idx >> 5, k = idx & 31;
            As[r][k] = X[(i0 + r) * Dd + kk + k];
            Bs[r][k] = Y[(j0 + r) * Dd + kk + k];
        }
        __syncthreads();
#pragma unroll
        for (int m = 0; m < 4; m++) {
            int r = ti + m * 8;
            float a = 0.f;
#pragma unroll
            for (int k = 0; k < 32; k++) {
                float d = As[r][k] - Bs[tj][k];
                a = fmaf(d, d, a);
            }
            acc[m] += a;
        }
        __syncthreads();
    }
    float e[4];
#pragma unroll
    for (int m = 0; m < 4; m++) {
        e[m] = sqrtf(acc[m]);
        Eo[(i0 + ti + m * 8) * Nn + j0 + tj] = e[m];
    }

    // ---- per-tile stats ----
    if (z == 0) {
        int t = ys[j0 + tj];                       // column class
#pragma unroll
        for (int m = 0; m < 4; m++)
            atomicAdd(&red[ysh[ti + m * 8] * 12 + t], e[m]);
        __syncthreads();
        if (tid < 144) P0T[tid * NTILE + tileIdx] = red[tid];
    } else {
        // pt row (j0+tj): 48B -> 3x float4
        const float4* p4 = (const float4*)(pt + (j0 + tj) * 12);
        float4 pa = p4[0], pb = p4[1], pc = p4[2];
        float pv[12] = {pa.x, pa.y, pa.z, pa.w, pb.x, pb.y, pb.z, pb.w,
                        pc.x, pc.y, pc.z, pc.w};
#pragma unroll
        for (int c = 0; c < 12; c++) {
            float a = 0.f;
            if (z == 1) {
#pragma unroll
                for (int m = 0; m < 4; m++)
                    a = fmaf(e[m], ptish[(ti + m * 8) * 12 + c], a);
            } else {
#pragma unroll
                for (int m = 0; m < 4; m++)
                    a += (ysh[ti + m * 8] == c) ? e[m] : 0.f;
            }
            float v = a * pv[c];
#pragma unroll
            for (int o = 32; o; o >>= 1) v += __shfl_xor(v, o, 64);
            if ((tid & 63) == 0) atomicAdd(&red[c], v);
        }
        __syncthreads();
        if (tid < 12) {
            if (z == 1) P1T[tid * NTILE + tileIdx] = red[tid];
            else        P2T[tid * NTILE + tileIdx] = red[tid];
        }
    }
}

// ---------- kernel 2: eval with inline prep (k1+k2+k3+inter) ----------
// One block per row i (384 blocks x 384 threads). Prologue reduces the
// transposed per-tile partials (48 targets x 8 lanes x 18 contiguous floats,
// shfl-reduced, NO atomics), derives bandwidth tables in LDS, then
// evaluates all RBF terms for pairs (i, j). s = ys[i] is block-uniform.
__global__ __launch_bounds__(384) void eval_kernel(
        const float* __restrict__ E, const int* __restrict__ ys,
        const float* __restrict__ pt, const float* __restrict__ P0T,
        const float* __restrict__ P1T, const float* __restrict__ P2T,
        float* __restrict__ out) {
    int i = blockIdx.x;
    int j = threadIdx.x;
    int s = ys[i];                          // uniform broadcast load
    __shared__ float st48[48];              // 0:sss(diag) 12:rowS 24:stt 36:sstd
    __shared__ float s_cs[12], s_ct[12];
    __shared__ float sh_ibwin[60];          // 1/bw(g_in), all classes
    __shared__ float sh_ibw2s[60];          // 1/bw(g2), row s
    __shared__ float sh_invptt[12];
    __shared__ float sh_invccs[12];         // 1/(cs[s]*cs[t'])
    __shared__ float sh_pti[12];            // pt[i][*]
    __shared__ float red[8];
    if (j >= 64 && j < 76)       s_cs[j - 64] = 0.f;
    else if (j >= 80 && j < 92)  s_ct[j - 80] = 0.f;
    else if (j >= 96 && j < 108) sh_pti[j - 96] = pt[i * 12 + (j - 96)];

    int t = ys[j];
    const float4* p4 = (const float4*)(pt + j * 12);
    float4 pa = p4[0], pb = p4[1], pc = p4[2];
    float ptj[12] = {pa.x, pa.y, pa.z, pa.w, pb.x, pb.y, pb.z, pb.w,
                     pc.x, pc.y, pc.z, pc.w};
    float e_ss = E[i * Nn + j];
    float e_tt = E[NN + i * Nn + j];
    float e_st = E[2 * NN + i * Nn + j];
    __syncthreads();

    // ---- cs / ct ----
    atomicAdd(&s_cs[t], 1.f);
#pragma unroll
    for (int c = 0; c < 12; c++) {
        float v = ptj[c];
#pragma unroll
        for (int o = 32; o; o >>= 1) v += __shfl_xor(v, o, 64);
        if ((j & 63) == 0) atomicAdd(&s_ct[c], v);
    }
    // ---- reduce transposed partials: 48 targets, 8 lanes each, coalesced ----
    {
        int g = j >> 3, k = j & 7;          // target, lane-in-group
        const float* src;
        if (g < 12)      src = P0T + (g * 13) * NTILE;           // sss diag
        else if (g < 24) src = P0T + (s * 12 + (g - 12)) * NTILE; // sst_s row s
        else if (g < 36) src = P1T + (g - 24) * NTILE;           // stt
        else             src = P2T + (g - 36) * NTILE;           // sstd
        float v = 0.f;
#pragma unroll
        for (int q = 0; q < 18; q++) v += src[k * 18 + q];       // 144 = 8*18
#pragma unroll
        for (int o = 1; o < 8; o <<= 1) v += __shfl_xor(v, o, 64);
        if (k == 0) st48[g] = v;            // direct store, no atomic
    }
    __syncthreads();
    // ---- derive bandwidth tables ----
    const float MUP[5] = {0.25f, 0.5f, 1.f, 2.f, 4.f};
    if (j < 12) {
        int c = j;
        float cs = s_cs[c], ct2 = s_ct[c];
        float g = (st48[c] + st48[24 + c] + 2.f * st48[36 + c])
                  / ((cs + ct2) * (cs + ct2));
#pragma unroll
        for (int k = 0; k < 5; k++)
            sh_ibwin[c * 5 + k] = 1.f / fmaxf(g * MUP[k], 1e-5f);
        sh_invptt[c] = 1.f / (ct2 * ct2);
    } else if (j >= 64 && j < 76) {
        int tp = j - 64;
        float css = s_cs[s], cst = s_cs[tp];
        float g2 = (st48[s] + st48[tp] + 2.f * st48[12 + tp])
                   / ((css + cst) * (css + cst));
#pragma unroll
        for (int k = 0; k < 5; k++)
            sh_ibw2s[tp * 5 + k] = 1.f / fmaxf(g2 * MUP[k], 1e-5f);
        sh_invccs[tp] = 1.f / (css * cst);
    }
    __syncthreads();
    float invpss_s = 1.f / (s_cs[s] * s_cs[s]);
    float invcst_s = 1.f / (s_cs[s] * s_ct[s]);

    float si = 0.f, se = 0.f;
    // ---- k2: target-target, soft probs, all 12 classes ----
#pragma unroll
    for (int c = 0; c < 12; c++) {
        float w = sh_pti[c] * ptj[c];
        si = fmaf(kern5(e_tt * w, &sh_ibwin[c * 5]) * w, sh_invptt[c], si);
    }
    // ---- k3: source-target, diagonal pair (class s) ----
    {
        float w = 0.f;                     // ptj[s] via unrolled select
#pragma unroll
        for (int c = 0; c < 12; c++) w = (c == s) ? ptj[c] : w;
        si = fmaf(-2.f * kern5(e_st * w, &sh_ibwin[s * 5]) * w, invcst_s, si);
    }
    // ---- k1 + inter on E_ss ----
    if (t == s) {
        si = fmaf(kern5(e_ss, &sh_ibwin[s * 5]), invpss_s, si);
        float ts = -kern5(e_ss, &sh_ibw2s[s * 5]);  // subtract tp==s term
#pragma unroll
        for (int tp = 0; tp < 12; tp++)
            ts += kern5(e_ss, &sh_ibw2s[tp * 5]);
        se = fmaf(2.f * ts, invpss_s, se);
    } else {
        se = fmaf(-2.f * kern5(e_ss, &sh_ibw2s[t * 5]), sh_invccs[t], se);
    }
    si = blockReduceSum(si, red);
    se = blockReduceSum(se, red);
    if (j == 0) {
        atomicAdd(&out[0], si * (1.f / 12.f));
        atomicAdd(&out[1], se * (1.f / 132.f));   // C*C - C = 132
    }
}

extern "C" void kernel_launch(void* const* d_in, const int* in_sizes, int n_in,
                              void* d_out, int out_size, void* d_ws, size_t ws_size,
                              hipStream_t stream) {
    (void)in_sizes; (void)n_in; (void)out_size; (void)ws_size;
    const float* sx = (const float*)d_in[0];   // src_x (384,256) f32
    const float* tx = (const float*)d_in[1];   // tgt_x (384,256) f32
    const int*   ys = (const int*)d_in[2];     // src_y (384,) i32
    const float* pt = (const float*)d_in[3];   // tgt_y (384,12) f32
    float* out = (float*)d_out;                // [intra, inter] f32
    float* ws  = (float*)d_ws;
    float* E   = ws;                           // 3 * NN floats
    float* P0T = ws + 3 * NN;                  // 144 stats x 144 tiles
    float* P1T = P0T + 144 * NTILE;            // 12 x 144
    float* P2T = P1T + 12 * NTILE;             // 12 x 144

    cdist_stats_kernel<<<dim3(12, 12, 3), 256, 0, stream>>>(sx, tx, ys, pt,
                                                            E, P0T, P1T, P2T, out);
    eval_kernel<<<384, 384, 0, stream>>>(E, ys, pt, P0T, P1T, P2T, out);
}

// Round 9
// 40.667 us; speedup vs baseline: 1.5225x; 1.2011x over previous
//
#include <hip/hip_runtime.h>
#include <math.h>

#define NN 147456   // 384*384
#define Nn 384
#define Dd 256
#define Cc 12
#define NTILE 144   // 12x12 tiles per matrix (32x32 each)
#define PADK 260    // row pitch in LDS (multiple of 4 for b128; 260%32=4 -> 4-way worst)

__device__ __forceinline__ float kern5(float d, const float* __restrict__ nibw) {
    // nibw[k] = -1/bw_k  (sign folded; clamps dropped: |err| <= 1e-5 per term)
    float acc = 0.f;
#pragma unroll
    for (int k = 0; k < 5; k++) acc += __expf(d * nibw[k]);
    return acc;
}

__device__ __forceinline__ float blockReduceSum(float v, float* sh) {
#pragma unroll
    for (int o = 32; o; o >>= 1) v += __shfl_xor(v, o, 64);
    __syncthreads();                       // protect sh reuse across calls
    if ((threadIdx.x & 63) == 0) sh[threadIdx.x >> 6] = v;
    __syncthreads();
    float r = 0.f;
    if (threadIdx.x == 0) {
        int nw = (int)(blockDim.x >> 6);
        for (int w = 0; w < nw; w++) r += sh[w];
    }
    return r;
}

// ---------- kernel 1: cdist (dot-product form) + per-tile stats (TRANSPOSED) ----------
// z=0: E_ss (src,src) -> P0T[stat(144)][tile(144)]  per-(s,t) sums
// z=1: E_tt (tgt,tgt) -> P1T[c(12)][tile(144)]      pt_i E pt_j sums
// z=2: E_st (src,tgt) -> P2T[c(12)][tile(144)]      (i in c) E pt_j sums
// Full K=256 staged once (no chunk barriers); d^2 = |a|^2+|b|^2-2ab (1 fma/elem);
// all LDS fragment reads are b128. Partials written unconditionally per tile.
__global__ __launch_bounds__(256, 2) void cdist_stats_kernel(
        const float* __restrict__ sx, const float* __restrict__ tx,
        const int* __restrict__ ys, const float* __restrict__ pt,
        float* __restrict__ Ebase, float* __restrict__ P0T,
        float* __restrict__ P1T, float* __restrict__ P2T,
        float* __restrict__ out) {
    int z = blockIdx.z;
    int tid = threadIdx.x;
    int i0 = blockIdx.y * 32, j0 = blockIdx.x * 32;
    int tileIdx = blockIdx.y * 12 + blockIdx.x;
    if (z == 0 && tileIdx == 0 && tid < 2) out[tid] = 0.f;

    const float* X = (z == 1) ? tx : sx;
    const float* Y = (z == 0) ? sx : tx;
    float* Eo = Ebase + z * NN;

    __shared__ float As[32 * PADK];
    __shared__ float Bs[32 * PADK];
    __shared__ float nA[32], nB[32];
    __shared__ float red[144];
    __shared__ int   ysh[32];
    __shared__ float ptish[384];

    // ---- stage full 32x256 panels (rows are contiguous in global) ----
    {
        const float4* Xv = (const float4*)(X + i0 * Dd);
        const float4* Yv = (const float4*)(Y + j0 * Dd);
#pragma unroll
        for (int it = 0; it < 8; it++) {
            int q = tid + it * 256;            // q in [0,2048): r=q>>6, quad=q&63
            int r = q >> 6, c = q & 63;
            *(float4*)&As[r * PADK + c * 4] = Xv[q];
            *(float4*)&Bs[r * PADK + c * 4] = Yv[q];
        }
    }
    __syncthreads();

    // ---- row/col norms (64 norms x 4 lanes) + small LDS init ----
    {
        int n = tid >> 2, qu = tid & 3;
        const float* src = (n < 32) ? &As[n * PADK] : &Bs[(n - 32) * PADK];
        float s = 0.f;
#pragma unroll
        for (int q = 0; q < 16; q++) {
            float4 v = *(const float4*)&src[(qu * 16 + q) * 4];
            s = fmaf(v.x, v.x, fmaf(v.y, v.y, fmaf(v.z, v.z, fmaf(v.w, v.w, s))));
        }
        s += __shfl_xor(s, 1, 64);
        s += __shfl_xor(s, 2, 64);
        if (qu == 0) { if (n < 32) nA[n] = s; else nB[n - 32] = s; }
    }
    if (tid < 32) ysh[tid] = ys[i0 + tid];
    if (tid < 144) red[tid] = 0.f;
    if (z == 1) { ptish[tid] = pt[i0 * 12 + tid]; if (tid < 128) ptish[256 + tid] = pt[i0 * 12 + 256 + tid]; }
    __syncthreads();

    // ---- dot products: thread (ti,tj) -> rows ti+8m, col tj ----
    int tj = tid & 31, ti = tid >> 5;
    float dot[4] = {0.f, 0.f, 0.f, 0.f};
#pragma unroll 4
    for (int q = 0; q < 64; q++) {
        float4 b = *(const float4*)&Bs[tj * PADK + q * 4];
#pragma unroll
        for (int m = 0; m < 4; m++) {
            float4 a = *(const float4*)&As[(ti + m * 8) * PADK + q * 4];
            dot[m] = fmaf(a.x, b.x, fmaf(a.y, b.y, fmaf(a.z, b.z, fmaf(a.w, b.w, dot[m]))));
        }
    }
    float e[4];
#pragma unroll
    for (int m = 0; m < 4; m++) {
        float d2 = nA[ti + m * 8] + nB[tj] - 2.f * dot[m];
        e[m] = sqrtf(fmaxf(d2, 0.f));
        Eo[(i0 + ti + m * 8) * Nn + j0 + tj] = e[m];
    }

    // ---- per-tile stats ----
    if (z == 0) {
        int t = ys[j0 + tj];                       // column class
#pragma unroll
        for (int m = 0; m < 4; m++)
            atomicAdd(&red[ysh[ti + m * 8] * 12 + t], e[m]);
        __syncthreads();
        if (tid < 144) P0T[tid * NTILE + tileIdx] = red[tid];
    } else {
        const float4* p4 = (const float4*)(pt + (j0 + tj) * 12);
        float4 pa = p4[0], pb = p4[1], pc = p4[2];
        float pv[12] = {pa.x, pa.y, pa.z, pa.w, pb.x, pb.y, pb.z, pb.w,
                        pc.x, pc.y, pc.z, pc.w};
#pragma unroll
        for (int c = 0; c < 12; c++) {
            float a = 0.f;
            if (z == 1) {
#pragma unroll
                for (int m = 0; m < 4; m++)
                    a = fmaf(e[m], ptish[(ti + m * 8) * 12 + c], a);
            } else {
#pragma unroll
                for (int m = 0; m < 4; m++)
                    a += (ysh[ti + m * 8] == c) ? e[m] : 0.f;
            }
            float v = a * pv[c];
#pragma unroll
            for (int o = 32; o; o >>= 1) v += __shfl_xor(v, o, 64);
            if ((tid & 63) == 0) atomicAdd(&red[c], v);
        }
        __syncthreads();
        if (tid < 12) {
            if (z == 1) P1T[tid * NTILE + tileIdx] = red[tid];
            else        P2T[tid * NTILE + tileIdx] = red[tid];
        }
    }
}

// ---------- kernel 2: eval with inline prep (k1+k2+k3+inter) ----------
// One block per row i (384 blocks x 384 threads). Prologue reduces the
// transposed per-tile partials (48 targets x 8 lanes x 18 contiguous floats,
// shfl-reduced, NO atomics), derives NEGATED-reciprocal bandwidth tables in
// LDS, then evaluates all RBF terms for pairs (i, j). s = ys[i] block-uniform.
__global__ __launch_bounds__(384) void eval_kernel(
        const float* __restrict__ E, const int* __restrict__ ys,
        const float* __restrict__ pt, const float* __restrict__ P0T,
        const float* __restrict__ P1T, const float* __restrict__ P2T,
        float* __restrict__ out) {
    int i = blockIdx.x;
    int j = threadIdx.x;
    int s = ys[i];                          // uniform broadcast load
    __shared__ float st48[48];              // 0:sss(diag) 12:rowS 24:stt 36:sstd
    __shared__ float s_cs[12], s_ct[12];
    __shared__ float sh_ibwin[60];          // -1/bw(g_in), all classes
    __shared__ float sh_ibw2s[60];          // -1/bw(g2), row s
    __shared__ float sh_invptt[12];
    __shared__ float sh_invccs[12];         // 1/(cs[s]*cs[t'])
    __shared__ float sh_pti[12];            // pt[i][*]
    __shared__ float red[8];
    if (j >= 64 && j < 76)       s_cs[j - 64] = 0.f;
    else if (j >= 80 && j < 92)  s_ct[j - 80] = 0.f;
    else if (j >= 96 && j < 108) sh_pti[j - 96] = pt[i * 12 + (j - 96)];

    int t = ys[j];
    const float4* p4 = (const float4*)(pt + j * 12);
    float4 pa = p4[0], pb = p4[1], pc = p4[2];
    float ptj[12] = {pa.x, pa.y, pa.z, pa.w, pb.x, pb.y, pb.z, pb.w,
                     pc.x, pc.y, pc.z, pc.w};
    float e_ss = E[i * Nn + j];
    float e_tt = E[NN + i * Nn + j];
    float e_st = E[2 * NN + i * Nn + j];
    __syncthreads();

    // ---- cs / ct ----
    atomicAdd(&s_cs[t], 1.f);
#pragma unroll
    for (int c = 0; c < 12; c++) {
        float v = ptj[c];
#pragma unroll
        for (int o = 32; o; o >>= 1) v += __shfl_xor(v, o, 64);
        if ((j & 63) == 0) atomicAdd(&s_ct[c], v);
    }
    // ---- reduce transposed partials: 48 targets, 8 lanes each, coalesced ----
    {
        int g = j >> 3, k = j & 7;          // target, lane-in-group
        const float* src;
        if (g < 12)      src = P0T + (g * 13) * NTILE;            // sss diag
        else if (g < 24) src = P0T + (s * 12 + (g - 12)) * NTILE; // sst_s row s
        else if (g < 36) src = P1T + (g - 24) * NTILE;            // stt
        else             src = P2T + (g - 36) * NTILE;            // sstd
        float v = 0.f;
#pragma unroll
        for (int q = 0; q < 18; q++) v += src[k * 18 + q];        // 144 = 8*18
#pragma unroll
        for (int o = 1; o < 8; o <<= 1) v += __shfl_xor(v, o, 64);
        if (k == 0) st48[g] = v;            // direct store, no atomic
    }
    __syncthreads();
    // ---- derive bandwidth tables (store -1/bw) ----
    const float MUP[5] = {0.25f, 0.5f, 1.f, 2.f, 4.f};
    if (j < 12) {
        int c = j;
        float cs = s_cs[c], ct2 = s_ct[c];
        float g = (st48[c] + st48[24 + c] + 2.f * st48[36 + c])
                  / ((cs + ct2) * (cs + ct2));
#pragma unroll
        for (int k = 0; k < 5; k++)
            sh_ibwin[c * 5 + k] = -1.f / fmaxf(g * MUP[k], 1e-5f);
        sh_invptt[c] = 1.f / (ct2 * ct2);
    } else if (j >= 64 && j < 76) {
        int tp = j - 64;
        float css = s_cs[s], cst = s_cs[tp];
        float g2 = (st48[s] + st48[tp] + 2.f * st48[12 + tp])
                   / ((css + cst) * (css + cst));
#pragma unroll
        for (int k = 0; k < 5; k++)
            sh_ibw2s[tp * 5 + k] = -1.f / fmaxf(g2 * MUP[k], 1e-5f);
        sh_invccs[tp] = 1.f / (css * cst);
    }
    __syncthreads();
    float invpss_s = 1.f / (s_cs[s] * s_cs[s]);
    float invcst_s = 1.f / (s_cs[s] * s_ct[s]);

    float si = 0.f, se = 0.f;
    // ---- k2: target-target, soft probs, all 12 classes ----
#pragma unroll
    for (int c = 0; c < 12; c++) {
        float w = sh_pti[c] * ptj[c];
        si = fmaf(kern5(e_tt * w, &sh_ibwin[c * 5]) * w, sh_invptt[c], si);
    }
    // ---- k3: source-target, diagonal pair (class s) ----
    {
        float w = 0.f;                     // ptj[s] via unrolled select
#pragma unroll
        for (int c = 0; c < 12; c++) w = (c == s) ? ptj[c] : w;
        si = fmaf(-2.f * kern5(e_st * w, &sh_ibwin[s * 5]) * w, invcst_s, si);
    }
    // ---- k1 + inter on E_ss ----
    if (t == s) {
        si = fmaf(kern5(e_ss, &sh_ibwin[s * 5]), invpss_s, si);
        float ts = -kern5(e_ss, &sh_ibw2s[s * 5]);  // subtract tp==s term
#pragma unroll
        for (int tp = 0; tp < 12; tp++)
            ts += kern5(e_ss, &sh_ibw2s[tp * 5]);
        se = fmaf(2.f * ts, invpss_s, se);
    } else {
        se = fmaf(-2.f * kern5(e_ss, &sh_ibw2s[t * 5]), sh_invccs[t], se);
    }
    si = blockReduceSum(si, red);
    se = blockReduceSum(se, red);
    if (j == 0) {
        atomicAdd(&out[0], si * (1.f / 12.f));
        atomicAdd(&out[1], se * (1.f / 132.f));   // C*C - C = 132
    }
}

extern "C" void kernel_launch(void* const* d_in, const int* in_sizes, int n_in,
                              void* d_out, int out_size, void* d_ws, size_t ws_size,
                              hipStream_t stream) {
    (void)in_sizes; (void)n_in; (void)out_size; (void)ws_size;
    const float* sx = (const float*)d_in[0];   // src_x (384,256) f32
    const float* tx = (const float*)d_in[1];   // tgt_x (384,256) f32
    const int*   ys = (const int*)d_in[2];     // src_y (384,) i32
    const float* pt = (const float*)d_in[3];   // tgt_y (384,12) f32
    float* out = (float*)d_out;                // [intra, inter] f32
    float* ws  = (float*)d_ws;
    float* E   = ws;                           // 3 * NN floats
    float* P0T = ws + 3 * NN;                  // 144 stats x 144 tiles
    float* P1T = P0T + 144 * NTILE;            // 12 x 144
    float* P2T = P1T + 12 * NTILE;             // 12 x 144

    cdist_stats_kernel<<<dim3(12, 12, 3), 256, 0, stream>>>(sx, tx, ys, pt,
                                                            E, P0T, P1T, P2T, out);
    eval_kernel<<<384, 384, 0, stream>>>(E, ys, pt, P0T, P1T, P2T, out);
}